// Round 1
// baseline (297.141 us; speedup 1.0000x reference)
//
#include <hip/hip_runtime.h>
#include <math.h>

// BalancedLoss: B=65536 rows, C=512 classes, pos_prop per class.
// loss = mean(bce(pred,target) * w), w depends only on (column, target value).
//
// History: R1 147us (libm VALU-bound) -> R3 107us (fast softplus + striped
// atomics) -> R4 plain stores -> R5/R6 latency-depth experiments (no change)
// -> R7/R8 occupancy 100% + nt loads (no change; harness 270.9us).
// This round (R9): rocprof shows harness poison fills (512MiB @ 6.9TB/s, 77us
// each) dominate the top-5; bl_partial <= 77us, i.e. ~3.5TB/s delivered vs
// 6.3TB/s achievable for its 268MB read. Theory: (256,8) -> 64-VGPR cap +
// runtime trip count + nt flag pin the load scheduler, not MLP (only ~9KB/CU
// in-flight needed).  Changes:
//   1. bl_partial: template RPB, full unroll, explicit 2-deep pipeline,
//      launch_bounds(256,4) for 128-VGPR headroom, plain (cached) loads.
//   2. out zeroed by bl_partial block 0 (drops the memset dispatch).
//   3. bl_reduce grid 16 -> 32 blocks (16 cols/block, 64B-coalesced).
// Predict: bl_partial ~43-55us @ ~6TB/s, total 271 -> ~235-250us.

constexpr int C = 512;
constexpr int C4 = 128;          // float4s per row
constexpr int PSTRIDE = 3 * C;   // 1536 floats per partial slot

__device__ __forceinline__ float softplus_neg_abs(float p) {
    // log(1 + exp(-|p|)) via v_exp/v_log; arg in (1,2], abs err ~1e-7.
    return __logf(1.0f + __expf(-fabsf(p)));
}

__device__ __forceinline__ void acc4(const float4& p, const float4& t,
                                     float4& a_s1, float4& a_st, float4& a_c1) {
    float b;
    b = fmaxf(p.x, 0.f) + softplus_neg_abs(p.x) - p.x * t.x;
    a_st.x += b; a_s1.x += b * t.x; a_c1.x += t.x;
    b = fmaxf(p.y, 0.f) + softplus_neg_abs(p.y) - p.y * t.y;
    a_st.y += b; a_s1.y += b * t.y; a_c1.y += t.y;
    b = fmaxf(p.z, 0.f) + softplus_neg_abs(p.z) - p.z * t.z;
    a_st.z += b; a_s1.z += b * t.z; a_c1.z += t.z;
    b = fmaxf(p.w, 0.f) + softplus_neg_abs(p.w) - p.w * t.w;
    a_st.w += b; a_s1.w += b * t.w; a_c1.w += t.w;
}

__device__ __forceinline__ void block_reduce_store(
    int tid, float* __restrict__ P,
    const float4& a_s1, const float4& a_st, const float4& a_c1)
{
    // Reduce the 2 rowlanes sharing each column-quad, plain coalesced stores.
    __shared__ float4 red[3][256];   // 12 KiB
    red[0][tid] = a_s1;
    red[1][tid] = a_st;
    red[2][tid] = a_c1;
    __syncthreads();
    if (tid < C4) {
        float* slot = P + (size_t)blockIdx.x * PSTRIDE;
        #pragma unroll
        for (int a = 0; a < 3; ++a) {
            float4 v0 = red[a][tid];
            float4 v1 = red[a][tid + 128];
            float4 v;
            v.x = v0.x + v1.x;
            v.y = v0.y + v1.y;
            v.z = v0.z + v1.z;
            v.w = v0.w + v1.w;
            ((float4*)(slot + a * C))[tid] = v;   // coalesced
        }
    }
}

// Fast path: compile-time rows-per-block, full unroll, 2-deep load pipeline.
// launch_bounds(256,4): <=128 VGPRs so the scheduler can cluster the 32
// independent dwordx4 loads well ahead of the exp/log chain. Occupancy 16
// waves/CU is ample: BW*latency needs only ~9KB/CU in flight.
template<int RPB>
__global__ __launch_bounds__(256, 4) void bl_partial_t(
    const float* __restrict__ pred, const float* __restrict__ targ,
    float* __restrict__ P, float* __restrict__ out)
{
    const int tid = threadIdx.x;
    const int col4 = tid & (C4 - 1);   // which float4 within the row
    const int rowlane = tid >> 7;      // 0..1 (2 rows in flight per block)
    if (blockIdx.x == 0 && tid == 0) *out = 0.f;   // replaces memset dispatch

    const size_t base = ((size_t)blockIdx.x * RPB + rowlane) * C4 + col4;
    const float4* p4 = (const float4*)pred + base;
    const float4* t4 = (const float4*)targ + base;

    float4 a_s1 = {0.f, 0.f, 0.f, 0.f};
    float4 a_st = {0.f, 0.f, 0.f, 0.f};
    float4 a_c1 = {0.f, 0.f, 0.f, 0.f};

    constexpr int NIT = RPB / 4;       // each iter consumes rows r and r+2

    // Prologue: batch 0 in flight.
    float4 p0 = p4[0];
    float4 p1 = p4[2 * C4];
    float4 t0 = t4[0];
    float4 t1 = t4[2 * C4];

    #pragma unroll
    for (int it = 0; it < NIT; ++it) {
        float4 cp0 = p0, cp1 = p1, ct0 = t0, ct1 = t1;   // SSA rename, no copy
        if (it + 1 < NIT) {            // issue batch it+1 before consuming it
            const float4* np = p4 + (size_t)(it + 1) * 4 * C4;
            const float4* nq = t4 + (size_t)(it + 1) * 4 * C4;
            p0 = np[0];
            p1 = np[2 * C4];
            t0 = nq[0];
            t1 = nq[2 * C4];
        }
        // Same per-thread accumulation order as previous rounds.
        acc4(cp0, ct0, a_s1, a_st, a_c1);
        acc4(cp1, ct1, a_s1, a_st, a_c1);
    }

    block_reduce_store(tid, P, a_s1, a_st, a_c1);
}

// Fallback for ws-shrunk grids (never hit at ws>=13MB): runtime trip count.
__global__ __launch_bounds__(256, 4) void bl_partial_rt(
    const float* __restrict__ pred, const float* __restrict__ targ,
    float* __restrict__ P, float* __restrict__ out, int rows_per_block)
{
    const int tid = threadIdx.x;
    const int col4 = tid & (C4 - 1);
    const int rowlane = tid >> 7;
    if (blockIdx.x == 0 && tid == 0) *out = 0.f;
    const long long row0 = (long long)blockIdx.x * rows_per_block;

    const float4* pred4 = (const float4*)pred;
    const float4* targ4 = (const float4*)targ;

    float4 a_s1 = {0.f, 0.f, 0.f, 0.f};
    float4 a_st = {0.f, 0.f, 0.f, 0.f};
    float4 a_c1 = {0.f, 0.f, 0.f, 0.f};

    for (int r = rowlane; r < rows_per_block; r += 4) {
        size_t i0 = (size_t)(row0 + r) * C4 + col4;
        size_t i1 = (size_t)(row0 + r + 2) * C4 + col4;
        float4 p0 = pred4[i0];
        float4 p1 = pred4[i1];
        float4 t0 = targ4[i0];
        float4 t1 = targ4[i1];
        acc4(p0, t0, a_s1, a_st, a_c1);
        acc4(p1, t1, a_s1, a_st, a_c1);
    }

    block_reduce_store(tid, P, a_s1, a_st, a_c1);
}

// 32 blocks x 512 threads; block owns 16 columns (4 float4). Sums P over G
// slots (G % 128 == 0), computes weights + term, one atomicAdd per block.
__global__ __launch_bounds__(512) void bl_reduce(
    const float* __restrict__ P, const float* __restrict__ pos_prop,
    float* __restrict__ out, int G, float Bf)
{
    const int tid = threadIdx.x;
    const int k = tid >> 2;          // 0..127: slot-lane
    const int g = tid & 3;           // 0..3: float4 within the 16 columns
    const int colbase = blockIdx.x * 16;

    float4 s1 = {0,0,0,0}, st = {0,0,0,0}, n1 = {0,0,0,0};
    for (int rb = k; rb < G; rb += 128) {
        const float* r0 = P + (size_t)rb * PSTRIDE + colbase;
        float4 a = ((const float4*)(r0))[g];          // 64B-coalesced per 4 lanes... per wave: 16 x 64B segments
        float4 b = ((const float4*)(r0 + C))[g];
        float4 c = ((const float4*)(r0 + 2 * C))[g];
        s1.x += a.x; s1.y += a.y; s1.z += a.z; s1.w += a.w;
        st.x += b.x; st.y += b.y; st.z += b.z; st.w += b.w;
        n1.x += c.x; n1.y += c.y; n1.z += c.z; n1.w += c.w;
    }

    __shared__ float4 red[3][512];   // 24 KiB
    red[0][tid] = s1; red[1][tid] = st; red[2][tid] = n1;
    __syncthreads();

    // Halving reduction over the 128 slot-lanes (k dimension).
    for (int stride = 256; stride >= 4; stride >>= 1) {
        if (tid < stride) {
            #pragma unroll
            for (int a = 0; a < 3; ++a) {
                float4 u = red[a][tid], v = red[a][tid + stride];
                u.x += v.x; u.y += v.y; u.z += v.z; u.w += v.w;
                red[a][tid] = u;
            }
        }
        __syncthreads();
    }

    if (tid < 64) {
        float term = 0.f;
        if (tid < 16) {   // totals are floats [0..15] of red[a]
            float s1c = ((const float*)red[0])[tid];
            float stc = ((const float*)red[1])[tid];
            float n1c = ((const float*)red[2])[tid];
            float bal = pos_prop[colbase + tid] * Bf;
            float n0 = Bf - n1c;
            float S0 = stc - s1c;
            float w1, w0;
            if (n1c >= bal) {              // positives are majority
                w1 = bal / n1c;
                w0 = (n0 > 0.f) ? (Bf - bal) / fmaxf(n0, 1.f) : 1.f;
            } else {                       // negatives are majority (n0 > B-bal >= 0)
                w0 = bal / n0;
                w1 = (n1c > 0.f) ? (Bf - bal) / fmaxf(n1c, 1.f) : 1.f;
            }
            term = w1 * s1c + w0 * S0;
        }
        #pragma unroll
        for (int off = 32; off > 0; off >>= 1)
            term += __shfl_down(term, off, 64);
        if (tid == 0)
            atomicAdd(out, term / (Bf * (float)C));   // 32 atomics total
    }
}

extern "C" void kernel_launch(void* const* d_in, const int* in_sizes, int n_in,
                              void* d_out, int out_size, void* d_ws, size_t ws_size,
                              hipStream_t stream) {
    const float* pred     = (const float*)d_in[0];
    const float* target   = (const float*)d_in[1];
    const float* pos_prop = (const float*)d_in[2];
    float* out = (float*)d_out;
    float* P = (float*)d_ws;

    const int Brows = in_sizes[0] / C;     // 65536
    int grid = 2048;                       // P = 2048 * 6 KB = 12.6 MB
    while ((size_t)grid * PSTRIDE * sizeof(float) > ws_size && grid > 256)
        grid >>= 1;                        // deterministic in ws_size; G stays %128
    const int rpb = Brows / grid;          // 32 rows per block at grid=2048

    if (grid == 2048 && rpb == 32) {
        bl_partial_t<32><<<2048, 256, 0, stream>>>(pred, target, P, out);
    } else {
        bl_partial_rt<<<grid, 256, 0, stream>>>(pred, target, P, out, rpb);
    }
    bl_reduce<<<C / 16, 512, 0, stream>>>(P, pos_prop, out, grid, (float)Brows);
}

// Round 2
// 269.535 us; speedup vs baseline: 1.1024x; 1.1024x over previous
//
#include <hip/hip_runtime.h>
#include <math.h>

// BalancedLoss: B=65536 rows, C=512 classes, pos_prop per class.
// loss = mean(bce(pred,target) * w), w depends only on (column, target value).
//
// History: R1 147us (libm VALU-bound) -> R3 107us (fast softplus + striped
// atomics) -> R4 plain stores -> R5/R6 latency-depth experiments (no change)
// -> R7/R8 occupancy ~100% + nt loads => 270.9us total, bl_partial ~76us
// (~3.5 TB/s delivered; FETCH 134MB = half the 268MB stream, rest L3).
// R9 (failed, 297us): dropped nt + manual 2-deep unrolled pipeline +
// launch_bounds(256,4). bl_partial 106us @ 2.53TB/s, occupancy 37%,
// VGPR still 64 -> the register-cap theory was wrong; nt/pipeline were
// the regression. R10 (this): revert bl_partial to the proven R7/R8 form
// (nt loads, (256,8), runtime loop), KEEP the two independent side-fixes:
// out zeroed in-kernel (drops memset dispatch) and 32-block bl_reduce.
// Predict: bl_partial ~76us, total ~264-268us.

constexpr int C = 512;
constexpr int C4 = 128;          // float4s per row
constexpr int PSTRIDE = 3 * C;   // 1536 floats per partial slot

typedef float floatv4 __attribute__((ext_vector_type(4)));

__device__ __forceinline__ float softplus_neg_abs(float p) {
    // log(1 + exp(-|p|)) via v_exp/v_log; arg in (1,2], abs err ~1e-7.
    return __logf(1.0f + __expf(-fabsf(p)));
}

__device__ __forceinline__ float4 ntload(const float4* p) {
    floatv4 v = __builtin_nontemporal_load((const floatv4*)p);
    return make_float4(v.x, v.y, v.z, v.w);
}

__device__ __forceinline__ void acc4(const float4& p, const float4& t,
                                     float4& a_s1, float4& a_st, float4& a_c1) {
    float b;
    b = fmaxf(p.x, 0.f) + softplus_neg_abs(p.x) - p.x * t.x;
    a_st.x += b; a_s1.x += b * t.x; a_c1.x += t.x;
    b = fmaxf(p.y, 0.f) + softplus_neg_abs(p.y) - p.y * t.y;
    a_st.y += b; a_s1.y += b * t.y; a_c1.y += t.y;
    b = fmaxf(p.z, 0.f) + softplus_neg_abs(p.z) - p.z * t.z;
    a_st.z += b; a_s1.z += b * t.z; a_c1.z += t.z;
    b = fmaxf(p.w, 0.f) + softplus_neg_abs(p.w) - p.w * t.w;
    a_st.w += b; a_s1.w += b * t.w; a_c1.w += t.w;
}

// Proven R7/R8 form: nt loads, runtime trip count, (256,8) -> 64 VGPR,
// 8 blocks/CU resident (12KiB LDS), simple strided loop. The only deltas
// vs the 270.9us source are the in-kernel out-zero and (elsewhere) the
// 32-block reduce.
__global__ __launch_bounds__(256, 8) void bl_partial(
    const float4* __restrict__ pred4, const float4* __restrict__ targ4,
    float* __restrict__ P, float* __restrict__ out, int rows_per_block)
{
    const int tid = threadIdx.x;
    const int col4 = tid & (C4 - 1);   // which float4 within the row
    const int rowlane = tid >> 7;      // 0..1 (2 rows in flight per block)
    if (blockIdx.x == 0 && tid == 0) *out = 0.f;   // replaces memset dispatch
    const long long row0 = (long long)blockIdx.x * rows_per_block;

    float4 a_s1 = {0.f, 0.f, 0.f, 0.f};
    float4 a_st = {0.f, 0.f, 0.f, 0.f};
    float4 a_c1 = {0.f, 0.f, 0.f, 0.f};

    for (int r = rowlane; r < rows_per_block; r += 4) {
        size_t i0 = (size_t)(row0 + r) * C4 + col4;
        size_t i1 = (size_t)(row0 + r + 2) * C4 + col4;
        float4 p0 = ntload(pred4 + i0);
        float4 p1 = ntload(pred4 + i1);
        float4 t0 = ntload(targ4 + i0);
        float4 t1 = ntload(targ4 + i1);
        acc4(p0, t0, a_s1, a_st, a_c1);
        acc4(p1, t1, a_s1, a_st, a_c1);
    }

    // Reduce the 2 rowlanes sharing each column-quad, plain coalesced stores.
    __shared__ float4 red[3][256];   // 12 KiB
    red[0][tid] = a_s1;
    red[1][tid] = a_st;
    red[2][tid] = a_c1;
    __syncthreads();
    if (tid < C4) {
        float* slot = P + (size_t)blockIdx.x * PSTRIDE;
        #pragma unroll
        for (int a = 0; a < 3; ++a) {
            float4 v0 = red[a][tid];
            float4 v1 = red[a][tid + 128];
            float4 v;
            v.x = v0.x + v1.x;
            v.y = v0.y + v1.y;
            v.z = v0.z + v1.z;
            v.w = v0.w + v1.w;
            ((float4*)(slot + a * C))[tid] = v;   // coalesced
        }
    }
}

// 32 blocks x 512 threads; block owns 16 columns (4 float4). Sums P over G
// slots (G % 128 == 0), computes weights + term, one atomicAdd per block.
__global__ __launch_bounds__(512) void bl_reduce(
    const float* __restrict__ P, const float* __restrict__ pos_prop,
    float* __restrict__ out, int G, float Bf)
{
    const int tid = threadIdx.x;
    const int k = tid >> 2;          // 0..127: slot-lane
    const int g = tid & 3;           // 0..3: float4 within the 16 columns
    const int colbase = blockIdx.x * 16;

    float4 s1 = {0,0,0,0}, st = {0,0,0,0}, n1 = {0,0,0,0};
    for (int rb = k; rb < G; rb += 128) {
        const float* r0 = P + (size_t)rb * PSTRIDE + colbase;
        float4 a = ((const float4*)(r0))[g];       // 16 x 64B segments per wave
        float4 b = ((const float4*)(r0 + C))[g];
        float4 c = ((const float4*)(r0 + 2 * C))[g];
        s1.x += a.x; s1.y += a.y; s1.z += a.z; s1.w += a.w;
        st.x += b.x; st.y += b.y; st.z += b.z; st.w += b.w;
        n1.x += c.x; n1.y += c.y; n1.z += c.z; n1.w += c.w;
    }

    __shared__ float4 red[3][512];   // 24 KiB
    red[0][tid] = s1; red[1][tid] = st; red[2][tid] = n1;
    __syncthreads();

    // Halving reduction over the 128 slot-lanes (k dimension).
    for (int stride = 256; stride >= 4; stride >>= 1) {
        if (tid < stride) {
            #pragma unroll
            for (int a = 0; a < 3; ++a) {
                float4 u = red[a][tid], v = red[a][tid + stride];
                u.x += v.x; u.y += v.y; u.z += v.z; u.w += v.w;
                red[a][tid] = u;
            }
        }
        __syncthreads();
    }

    if (tid < 64) {
        float term = 0.f;
        if (tid < 16) {   // totals are floats [0..15] of red[a]
            float s1c = ((const float*)red[0])[tid];
            float stc = ((const float*)red[1])[tid];
            float n1c = ((const float*)red[2])[tid];
            float bal = pos_prop[colbase + tid] * Bf;
            float n0 = Bf - n1c;
            float S0 = stc - s1c;
            float w1, w0;
            if (n1c >= bal) {              // positives are majority
                w1 = bal / n1c;
                w0 = (n0 > 0.f) ? (Bf - bal) / fmaxf(n0, 1.f) : 1.f;
            } else {                       // negatives are majority (n0 > B-bal >= 0)
                w0 = bal / n0;
                w1 = (n1c > 0.f) ? (Bf - bal) / fmaxf(n1c, 1.f) : 1.f;
            }
            term = w1 * s1c + w0 * S0;
        }
        #pragma unroll
        for (int off = 32; off > 0; off >>= 1)
            term += __shfl_down(term, off, 64);
        if (tid == 0)
            atomicAdd(out, term / (Bf * (float)C));   // 32 atomics total
    }
}

extern "C" void kernel_launch(void* const* d_in, const int* in_sizes, int n_in,
                              void* d_out, int out_size, void* d_ws, size_t ws_size,
                              hipStream_t stream) {
    const float* pred     = (const float*)d_in[0];
    const float* target   = (const float*)d_in[1];
    const float* pos_prop = (const float*)d_in[2];
    float* out = (float*)d_out;
    float* P = (float*)d_ws;

    const int Brows = in_sizes[0] / C;     // 65536
    int grid = 2048;                       // P = 2048 * 6 KB = 12.6 MB
    while ((size_t)grid * PSTRIDE * sizeof(float) > ws_size && grid > 256)
        grid >>= 1;                        // deterministic in ws_size; G stays %128
    const int rpb = Brows / grid;          // 32 rows per block at grid=2048

    bl_partial<<<grid, 256, 0, stream>>>((const float4*)pred, (const float4*)target,
                                         P, out, rpb);
    bl_reduce<<<C / 16, 512, 0, stream>>>(P, pos_prop, out, grid, (float)Brows);
}